// Round 7
// baseline (501.213 us; speedup 1.0000x reference)
//
#include <hip/hip_runtime.h>
#include <hip/hip_cooperative_groups.h>

namespace cg = cooperative_groups;

#define NT    85
#define BINS  28
#define NTB   (NT * BINS)            // 2380
#define LUT_ELEMS (NT * NT * BINS)   // 202300
#define CUT2  (19.6f * 19.6f)
#define ROWCAP 8
#define COLCAP 8

__device__ __forceinline__ unsigned bf16r(float x) {
    unsigned b = __float_as_uint(x);
    return (b + 0x7FFFu + ((b >> 16) & 1u)) >> 16;   // RTNE to bf16
}

// ============================================================================
// Fused cooperative kernel: LUT pack + (sort by last block) -> pairs -> reduce
// grid = TI*(TJ+4-4*TI) blocks (1088 @ N=8192), block = 256 threads.
// Tiles: 512 i-atoms x 64 j-atoms, 2 i per thread, j broadcast from LDS.
// ============================================================================
__global__ __launch_bounds__(256) void fused_k(
    const float* __restrict__ pot, const float* __restrict__ coords,
    const int* __restrict__ res, const int* __restrict__ type,
    unsigned* __restrict__ pk, float4* __restrict__ pc,
    float* __restrict__ partial, float* __restrict__ out,
    int N, int TI, int TJ) {

    cg::grid_group grid = cg::this_grid();

    __shared__ float4   jtile[64];
    __shared__ unsigned lrow[ROWCAP * COLCAP * BINS];   // 7168 B; reused as hist
    __shared__ float    wsum[4];

    const int tid = threadIdx.x;
    const int bid = blockIdx.x;
    const int nb  = (int)gridDim.x;

    // ---- phase A: pack LUT (strided over all blocks); last block sorts atoms
    int idx = bid * 256 + tid;
    if (idx < LUT_ELEMS) {
        int d  = idx % BINS;
        int ab = idx / BINS;
        int d1 = (d + 1 < BINS) ? d + 1 : BINS - 1;
        pk[idx] = (bf16r(pot[ab * BINS + d1]) << 16) | bf16r(pot[idx]);
    }
    if (bid == nb - 1) {
        int* h  = (int*)lrow;      // 85 ints
        int* of = h + 128;         // 85 ints
        if (tid < NT) h[tid] = 0;
        __syncthreads();
        for (int i = tid; i < N; i += 256) atomicAdd(&h[type[i]], 1);
        __syncthreads();
        if (tid == 0) { int s = 0; for (int t = 0; t < NT; ++t) { of[t] = s; s += h[t]; } }
        __syncthreads();
        for (int i = tid; i < N; i += 256) {
            int t = type[i];
            int p = atomicAdd(&of[t], 1);
            pc[p] = make_float4(coords[3 * i], coords[3 * i + 1], coords[3 * i + 2],
                                __int_as_float((t << 10) | res[i]));
        }
    }
    grid.sync();

    // ---- phase B: pairs. cum(ri) = ri*(TJ+4-4*ri); cj = 8*ri + (k - cum)
    {
        int k = bid;
        double A = (double)TJ + 4.0;
        int ri = (int)((A - sqrt(A * A - 16.0 * (double)k)) / 8.0);
        if (ri < 0) ri = 0;
        if (ri > TI - 1) ri = TI - 1;
        while (ri > 0 && ri * (TJ + 4 - 4 * ri) > k) --ri;
        while (ri + 1 < TI && (ri + 1) * (TJ + 4 - 4 * (ri + 1)) <= k) ++ri;
        int cj = 8 * ri + (k - ri * (TJ + 4 - 4 * ri));

        int bi = ri * 512, bj = cj * 64;

        if (tid < 64) jtile[tid] = pc[bj + tid];
        float4 ci0 = pc[bi + tid];
        float4 ci1 = pc[bi + 256 + tid];

        const int* pci = (const int*)pc;
        int tA = pci[4 * bi + 3] >> 10;
        int tB = pci[4 * (bi + 511) + 3] >> 10;
        int tC = pci[4 * bj + 3] >> 10;
        int tD = pci[4 * (bj + 63) + 3] >> 10;
        int nrow = tB - tA + 1, ncol = tD - tC + 1;
        bool useLds = (nrow <= ROWCAP) && (ncol <= COLCAP);

        if (useLds) {
            int tot = nrow * ncol * BINS;
            for (int e = tid; e < tot; e += 256) {
                int d  = e % BINS;
                int rc = e / BINS;
                int cc = rc % ncol;
                int rr = rc / ncol;
                lrow[e] = pk[((tA + rr) * NT + (tC + cc)) * BINS + d];
            }
        }
        __syncthreads();

        int w0 = __float_as_int(ci0.w), w1 = __float_as_int(ci1.w);
        int ires0 = w0 & 1023, ires1 = w1 & 1023;
        int it0 = w0 >> 10, it1 = w1 >> 10;
        int rb0 = (it0 - tA) * (ncol * BINS);
        int rb1 = (it1 - tA) * (ncol * BINS);
        int gb0 = it0 * NTB;
        int gb1 = it1 * NTB;
        bool straddle = (cj < 8 * ri + 8);
        int ig0 = straddle ? (bi + tid)       : -1;
        int ig1 = straddle ? (bi + 256 + tid) : -1;

        float acc0 = 0.f, acc1 = 0.f;
        int woff = (tid >> 6) << 4;   // stagger waves; each thread covers all 64 j

#define PAIR(CI, IRES, IG, RBASE, ACC) do {                                   \
    float dx = (CI).x - cj4.x, dy = (CI).y - cj4.y, dz = (CI).z - cj4.z;      \
    float d2 = fmaf(dx, dx, fmaf(dy, dy, dz * dz));                           \
    int sep = (IRES) - jres; sep = sep < 0 ? -sep : sep;                      \
    bool v = (sep > 2) & (d2 < CUT2) & (jg > (IG));                           \
    float dist  = __builtin_amdgcn_sqrtf(d2);                                 \
    float ds    = dist * (1.0f / 0.7f);                                       \
    float dsc   = fminf(ds, 27.0f);                                           \
    int   d0    = (int)dsc;                                                   \
    float alpha = ds - (float)d0;                                             \
    unsigned u  = SRC[(RBASE) + jcb + d0];                                    \
    float e0 = __uint_as_float(u << 16);                                      \
    float e1 = __uint_as_float(u & 0xFFFF0000u);                              \
    float en = fmaf(alpha, e1 - e0, e0);                                      \
    ACC += v ? en : 0.0f;                                                     \
} while (0)

        if (useLds) {
            #pragma unroll 4
            for (int s = 0; s < 64; ++s) {
                int j = (s + woff) & 63;
                float4 cj4 = jtile[j];
                int wj   = __builtin_amdgcn_readfirstlane(__float_as_int(cj4.w));
                int jres = wj & 1023;
                int jcb  = ((wj >> 10) - tC) * BINS;
                int jg   = bj + j;
#define SRC lrow
                PAIR(ci0, ires0, ig0, rb0, acc0);
                PAIR(ci1, ires1, ig1, rb1, acc1);
#undef SRC
            }
        } else {
            #pragma unroll 2
            for (int s = 0; s < 64; ++s) {
                int j = (s + woff) & 63;
                float4 cj4 = jtile[j];
                int wj   = __builtin_amdgcn_readfirstlane(__float_as_int(cj4.w));
                int jres = wj & 1023;
                int jcb  = (wj >> 10) * BINS;
#define SRC pk
                int jg   = bj + j;
                PAIR(ci0, ires0, ig0, gb0, acc0);
                PAIR(ci1, ires1, ig1, gb1, acc1);
#undef SRC
            }
        }
#undef PAIR

        float acc = acc0 + acc1;
        for (int off = 32; off > 0; off >>= 1)
            acc += __shfl_down(acc, off, 64);
        if ((tid & 63) == 0) wsum[tid >> 6] = acc;
        __syncthreads();
        if (tid == 0) partial[bid] = (wsum[0] + wsum[1]) + (wsum[2] + wsum[3]);
    }
    grid.sync();

    // ---- phase C: block 0 reduces partials -> out[0]
    if (bid == 0) {
        float a = 0.f;
        for (int i = tid; i < nb; i += 256) a += partial[i];
        for (int off = 32; off > 0; off >>= 1)
            a += __shfl_down(a, off, 64);
        if ((tid & 63) == 0) wsum[tid >> 6] = a;
        __syncthreads();
        if (tid == 0) out[0] = (wsum[0] + wsum[1]) + (wsum[2] + wsum[3]);
    }
}

// ============================================================================
// Fallback pipeline (proven R6 path) — used if cooperative launch unavailable
// ============================================================================
__global__ __launch_bounds__(256) void prep_k(const float* __restrict__ pot,
                                              const int* __restrict__ type, int N,
                                              unsigned* __restrict__ pk,
                                              int* __restrict__ offs) {
    if ((int)blockIdx.x == (int)gridDim.x - 1) {
        __shared__ int h[NT];
        for (int t = threadIdx.x; t < NT; t += 256) h[t] = 0;
        __syncthreads();
        for (int i = threadIdx.x; i < N; i += 256) atomicAdd(&h[type[i]], 1);
        __syncthreads();
        if (threadIdx.x == 0) {
            int s = 0;
            for (int t = 0; t < NT; ++t) { offs[t] = s; s += h[t]; }
        }
    }
    int idx = blockIdx.x * 256 + threadIdx.x;
    if (idx < LUT_ELEMS) {
        int d  = idx % BINS;
        int ab = idx / BINS;
        int d1 = (d + 1 < BINS) ? d + 1 : BINS - 1;
        pk[idx] = (bf16r(pot[ab * BINS + d1]) << 16) | bf16r(pot[idx]);
    }
}

__global__ void scatter_k(const float* __restrict__ coords, const int* __restrict__ res,
                          const int* __restrict__ type, int* __restrict__ offs,
                          float4* __restrict__ pc, int N) {
    int i = blockIdx.x * blockDim.x + threadIdx.x;
    if (i >= N) return;
    int t = type[i];
    int p = atomicAdd(&offs[t], 1);
    pc[p] = make_float4(coords[3 * i], coords[3 * i + 1], coords[3 * i + 2],
                        __int_as_float((t << 10) | res[i]));
}

__global__ __launch_bounds__(128) void dfire_pairs6(
    const float4*  __restrict__ pc,
    const unsigned* __restrict__ pk,
    float* __restrict__ partial, int TI, int TJ) {

    __shared__ float4   jtile[128];
    __shared__ unsigned lrow[ROWCAP * COLCAP * BINS];
    __shared__ float    wsum[2];

    int k = blockIdx.x;
    double A = (double)TJ + 1.0;
    int ri = (int)((A - sqrt(A * A - 4.0 * (double)k)) * 0.5);
    if (ri < 0) ri = 0;
    if (ri > TI - 1) ri = TI - 1;
    while (ri > 0 && ri * (TJ + 1 - ri) > k) --ri;
    while (ri + 1 < TI && (ri + 1) * (TJ + 1 - (ri + 1)) <= k) ++ri;
    int cj = 2 * ri + (k - ri * (TJ + 1 - ri));

    int bi = ri * 256, bj = cj * 128;
    int tid = threadIdx.x;

    jtile[tid] = pc[bj + tid];
    float4 ci0 = pc[bi + tid];
    float4 ci1 = pc[bi + 128 + tid];

    const int* pci = (const int*)pc;
    int tA = pci[4 * bi + 3] >> 10;
    int tB = pci[4 * (bi + 255) + 3] >> 10;
    int tC = pci[4 * bj + 3] >> 10;
    int tD = pci[4 * (bj + 127) + 3] >> 10;
    int nrow = tB - tA + 1, ncol = tD - tC + 1;
    bool useLds = (nrow <= ROWCAP) && (ncol <= COLCAP);

    if (useLds) {
        int tot = nrow * ncol * BINS;
        for (int e = tid; e < tot; e += 128) {
            int d  = e % BINS;
            int rc = e / BINS;
            int cc = rc % ncol;
            int rr = rc / ncol;
            lrow[e] = pk[((tA + rr) * NT + (tC + cc)) * BINS + d];
        }
    }
    __syncthreads();

    int w0 = __float_as_int(ci0.w), w1 = __float_as_int(ci1.w);
    int ires0 = w0 & 1023, ires1 = w1 & 1023;
    int it0 = w0 >> 10, it1 = w1 >> 10;
    int rb0 = (it0 - tA) * (ncol * BINS);
    int rb1 = (it1 - tA) * (ncol * BINS);
    int gb0 = it0 * NTB;
    int gb1 = it1 * NTB;
    bool straddle = (cj <= 2 * ri + 1);
    int ig0 = straddle ? (bi + tid)       : -1;
    int ig1 = straddle ? (bi + 128 + tid) : -1;

    float acc0 = 0.f, acc1 = 0.f;
    int w = tid >> 6;

#define PAIR(CI, IRES, IG, RBASE, ACC) do {                                   \
    float dx = (CI).x - cj4.x, dy = (CI).y - cj4.y, dz = (CI).z - cj4.z;      \
    float d2 = fmaf(dx, dx, fmaf(dy, dy, dz * dz));                           \
    int sep = (IRES) - jres; sep = sep < 0 ? -sep : sep;                      \
    bool v = (sep > 2) & (d2 < CUT2) & (jg > (IG));                           \
    float dist  = __builtin_amdgcn_sqrtf(d2);                                 \
    float ds    = dist * (1.0f / 0.7f);                                       \
    float dsc   = fminf(ds, 27.0f);                                           \
    int   d0    = (int)dsc;                                                   \
    float alpha = ds - (float)d0;                                             \
    unsigned u  = SRC[(RBASE) + jcb + d0];                                    \
    float e0 = __uint_as_float(u << 16);                                      \
    float e1 = __uint_as_float(u & 0xFFFF0000u);                              \
    float en = fmaf(alpha, e1 - e0, e0);                                      \
    ACC += v ? en : 0.0f;                                                     \
} while (0)

    if (useLds) {
        #pragma unroll 4
        for (int s = 0; s < 128; ++s) {
            int j = (s + (w << 6)) & 127;
            float4 cj4 = jtile[j];
            int wj  = __builtin_amdgcn_readfirstlane(__float_as_int(cj4.w));
            int jres = wj & 1023;
            int jcb  = ((wj >> 10) - tC) * BINS;
            int jg   = bj + j;
#define SRC lrow
            PAIR(ci0, ires0, ig0, rb0, acc0);
            PAIR(ci1, ires1, ig1, rb1, acc1);
#undef SRC
        }
    } else {
        #pragma unroll 2
        for (int s = 0; s < 128; ++s) {
            int j = (s + (w << 6)) & 127;
            float4 cj4 = jtile[j];
            int wj  = __builtin_amdgcn_readfirstlane(__float_as_int(cj4.w));
            int jres = wj & 1023;
            int jcb  = (wj >> 10) * BINS;
            int jg   = bj + j;
#define SRC pk
            PAIR(ci0, ires0, ig0, gb0, acc0);
            PAIR(ci1, ires1, ig1, gb1, acc1);
#undef SRC
        }
    }
#undef PAIR

    float acc = acc0 + acc1;
    for (int off = 32; off > 0; off >>= 1)
        acc += __shfl_down(acc, off, 64);
    if ((tid & 63) == 0) wsum[tid >> 6] = acc;
    __syncthreads();
    if (tid == 0) partial[blockIdx.x] = wsum[0] + wsum[1];
}

__global__ __launch_bounds__(256) void reduce_k(const float* __restrict__ p, int n,
                                                float* __restrict__ out) {
    __shared__ float ws[4];
    float a = 0.f;
    for (int i = threadIdx.x; i < n; i += 256) a += p[i];
    for (int off = 32; off > 0; off >>= 1)
        a += __shfl_down(a, off, 64);
    if ((threadIdx.x & 63) == 0) ws[threadIdx.x >> 6] = a;
    __syncthreads();
    if (threadIdx.x == 0) out[0] = (ws[0] + ws[1]) + (ws[2] + ws[3]);
}

__global__ __launch_bounds__(256) void dfire_pairs_fb(
    const float* __restrict__ coords, const int* __restrict__ res,
    const int* __restrict__ type, const float* __restrict__ pot,
    float* __restrict__ out, int T) {

    __shared__ float jx[128], jy[128], jz[128];
    __shared__ int   jres[128], jtype[128];

    int k = blockIdx.x;
    int r = (int)((2.0 * T + 1.0 - sqrt((2.0 * T + 1.0) * (2.0 * T + 1.0) - 8.0 * (double)k)) * 0.5);
    if (r < 0) r = 0;
    if (r > T - 1) r = T - 1;
    while (r > 0 && (r * T - r * (r - 1) / 2) > k) --r;
    while (((r + 1) * T - (r + 1) * r / 2) <= k) ++r;
    int c = r + (k - (r * T - r * (r - 1) / 2));

    int bi = r * 128, bj = c * 128;
    int tid = threadIdx.x;
    if (tid < 128) {
        int gj = bj + tid;
        jx[tid] = coords[3 * gj]; jy[tid] = coords[3 * gj + 1]; jz[tid] = coords[3 * gj + 2];
        jres[tid] = res[gj]; jtype[tid] = type[gj];
    }
    int ii = tid & 127;
    int gi = bi + ii;
    float ix = coords[3 * gi], iy = coords[3 * gi + 1], iz = coords[3 * gi + 2];
    int iresv = res[gi], it = type[gi];
    int ii_eff = (bi == bj) ? ii : -1;
    __syncthreads();

    float acc = 0.f;
    int jj = tid >> 7;
    for (int s = 0; s < 64; ++s, jj += 2) {
        float dx = ix - jx[jj], dy = iy - jy[jj], dz = iz - jz[jj];
        float d2 = dx * dx + dy * dy + dz * dz;
        float dist = sqrtf(d2) + 1e-8f;
        int sep = abs(iresv - jres[jj]);
        bool v = (sep > 2) & (dist < 19.6f) & (jj > ii_eff);
        if (v) {
            float ds = dist * (1.0f / 0.7f);
            int d0 = (int)fminf(ds, 27.0f);
            int d1 = (d0 + 1 < BINS) ? d0 + 1 : BINS - 1;
            float alpha = ds - (float)d0;
            int row = (jtype[jj] * NT + it) * BINS;
            float e0 = pot[row + d0], e1 = pot[row + d1];
            acc += e0 + alpha * (e1 - e0);
        }
    }
    for (int off = 32; off > 0; off >>= 1)
        acc += __shfl_down(acc, off, 64);
    if ((tid & 63) == 0) atomicAdd(out, acc);
}

extern "C" void kernel_launch(void* const* d_in, const int* in_sizes, int n_in,
                              void* d_out, int out_size, void* d_ws, size_t ws_size,
                              hipStream_t stream) {
    const float* coords = (const float*)d_in[0];
    const float* pot    = (const float*)d_in[1];
    const int*   res    = (const int*)d_in[2];
    const int*   type   = (const int*)d_in[3];
    // d_in[4], d_in[5] (i_idx/j_idx) unused: pairs generated from triu structure.

    const int N = in_sizes[2];
    float* out = (float*)d_out;

    const size_t pkBytes   = (((size_t)(LUT_ELEMS + 1) * 4) + 15) & ~(size_t)15;
    const size_t pcBytes   = (size_t)N * sizeof(float4);
    const size_t offsBytes = 128 * sizeof(int);
    const size_t partBytes = 4096 * sizeof(float);
    const size_t need = pkBytes + pcBytes + offsBytes + partBytes;

    if (ws_size >= need && (N % 512) == 0) {
        char* w = (char*)d_ws;
        unsigned* pk      = (unsigned*)w;   w += pkBytes;
        float4*   pc      = (float4*)w;     w += pcBytes;
        int*      offs    = (int*)w;        w += offsBytes;
        float*    partial = (float*)w;

        int coop = 0, dev = 0;
        hipGetDevice(&dev);
        hipDeviceGetAttribute(&coop, hipDeviceAttributeCooperativeLaunch, dev);

        if (coop) {
            int TI = N / 512, TJ = N / 64;
            int nblk = TI * (TJ + 4 - 4 * TI);   // 1088 @ N=8192
            const float* a_pot = pot; const float* a_co = coords;
            const int* a_res = res; const int* a_ty = type;
            unsigned* a_pk = pk; float4* a_pc = pc; float* a_pa = partial;
            float* a_out = out; int a_N = N, a_TI = TI, a_TJ = TJ;
            void* args[] = { &a_pot, &a_co, &a_res, &a_ty, &a_pk, &a_pc,
                             &a_pa, &a_out, &a_N, &a_TI, &a_TJ };
            hipError_t e = hipLaunchCooperativeKernel((const void*)fused_k,
                                dim3(nblk), dim3(256), args, 0, stream);
            if (e == hipSuccess) return;
            (void)hipGetLastError();   // clear; fall through to classic pipeline
        }

        // classic 4-kernel pipeline (proven R6 path)
        int TI2 = N / 256, TJ2 = N / 128;
        int nblk2 = TI2 * (TJ2 + 1 - TI2);
        const int prepBlocks = (LUT_ELEMS + 255) / 256;
        prep_k<<<prepBlocks + 1, 256, 0, stream>>>(pot, type, N, pk, offs);
        scatter_k<<<(N + 255) / 256, 256, 0, stream>>>(coords, res, type, offs, pc, N);
        dfire_pairs6<<<nblk2, 128, 0, stream>>>(pc, pk, partial, TI2, TJ2);
        reduce_k<<<1, 256, 0, stream>>>(partial, nblk2, out);
    } else {
        hipMemsetAsync(out, 0, sizeof(float), stream);
        const int T = N / 128;
        dfire_pairs_fb<<<T * (T + 1) / 2, 256, 0, stream>>>(coords, res, type, pot, out, T);
    }
}

// Round 8
// 322.339 us; speedup vs baseline: 1.5549x; 1.5549x over previous
//
#include <hip/hip_runtime.h>

#define NT    85
#define BINS  28
#define NTB   (NT * BINS)            // 2380
#define LUT_ELEMS (NT * NT * BINS)   // 202300
#define CUT2  (19.6f * 19.6f)
#define ROWCAP 8
#define COLCAP 8

__device__ __forceinline__ unsigned bf16r(float x) {
    unsigned b = __float_as_uint(x);
    return (b + 0x7FFFu + ((b >> 16) & 1u)) >> 16;   // RTNE to bf16
}

// ---- K1: pack LUT -> u32(bf16(e[d+1])<<16 | bf16(e[d])); last block: hist+scan
__global__ __launch_bounds__(256) void prep_k(const float* __restrict__ pot,
                                              const int* __restrict__ type, int N,
                                              unsigned* __restrict__ pk,
                                              int* __restrict__ offs) {
    if ((int)blockIdx.x == (int)gridDim.x - 1) {
        __shared__ int h[NT];
        for (int t = threadIdx.x; t < NT; t += 256) h[t] = 0;
        __syncthreads();
        for (int i = threadIdx.x; i < N; i += 256) atomicAdd(&h[type[i]], 1);
        __syncthreads();
        if (threadIdx.x == 0) {
            int s = 0;
            for (int t = 0; t < NT; ++t) { offs[t] = s; s += h[t]; }
        }
        return;
    }
    int idx = blockIdx.x * 256 + threadIdx.x;
    if (idx < LUT_ELEMS) {
        int d  = idx % BINS;
        int ab = idx / BINS;
        int d1 = (d + 1 < BINS) ? d + 1 : BINS - 1;
        pk[idx] = (bf16r(pot[ab * BINS + d1]) << 16) | bf16r(pot[idx]);
    }
}

// ---- K2: scatter atoms into type-sorted order; pack (x,y,z, type<<10|res)
__global__ void scatter_k(const float* __restrict__ coords, const int* __restrict__ res,
                          const int* __restrict__ type, int* __restrict__ offs,
                          float4* __restrict__ pc, int N) {
    int i = blockIdx.x * blockDim.x + threadIdx.x;
    if (i >= N) return;
    int t = type[i];
    int p = atomicAdd(&offs[t], 1);
    pc[p] = make_float4(coords[3 * i], coords[3 * i + 1], coords[3 * i + 2],
                        __int_as_float((t << 10) | res[i]));
}

// ---- K3: pairs. 128i x 128j, 256 threads (2 threads/i, even/odd j split).
//      2080 blocks -> 8.1 waves/SIMD TLP. LUT rows in LDS (bf16x2), 1 ds_read_b32/pair.
//      __launch_bounds__(256,8): cap VGPRs so all 8 waves/SIMD are resident.
__global__ __launch_bounds__(256, 8) void dfire_pairs8(
    const float4*  __restrict__ pc,
    const unsigned* __restrict__ pk,
    float* __restrict__ partial, int T) {

    __shared__ float4   jtile[128];
    __shared__ unsigned lrow[ROWCAP * COLCAP * BINS];   // 7168 B
    __shared__ float    wsum[4];

    // blockIdx -> (r,c) tile in upper triangle (r <= c); f(r) = r*T - r*(r-1)/2
    int k = blockIdx.x;
    int r = (int)((2.0 * T + 1.0 - sqrt((2.0 * T + 1.0) * (2.0 * T + 1.0) - 8.0 * (double)k)) * 0.5);
    if (r < 0) r = 0;
    if (r > T - 1) r = T - 1;
    while (r > 0 && (r * T - r * (r - 1) / 2) > k) --r;
    while (((r + 1) * T - (r + 1) * r / 2) <= k) ++r;
    int c = r + (k - (r * T - r * (r - 1) / 2));

    int bi = r * 128, bj = c * 128;
    int tid = threadIdx.x;

    if (tid < 128) jtile[tid] = pc[bj + tid];

    int ii = tid & 127;
    float4 ci = pc[bi + ii];

    // type ranges (atoms type-sorted -> contiguous)
    const int* pci = (const int*)pc;
    int tA = pci[4 * bi + 3] >> 10;
    int tB = pci[4 * (bi + 127) + 3] >> 10;
    int tC = pci[4 * bj + 3] >> 10;
    int tD = pci[4 * (bj + 127) + 3] >> 10;
    int nrow = tB - tA + 1, ncol = tD - tC + 1;
    bool useLds = (nrow <= ROWCAP) && (ncol <= COLCAP);

    if (useLds) {
        int tot = nrow * ncol * BINS;
        for (int e = tid; e < tot; e += 256) {
            int d  = e % BINS;
            int rc = e / BINS;
            int cc = rc % ncol;
            int rr = rc / ncol;
            lrow[e] = pk[((tA + rr) * NT + (tC + cc)) * BINS + d];
        }
    }
    __syncthreads();

    int wi   = __float_as_int(ci.w);
    int ires = wi & 1023;
    int it   = wi >> 10;
    int rbL  = (it - tA) * (ncol * BINS);   // LDS row base
    int rbG  = it * NTB;                    // global row base
    int ii_eff = (bi == bj) ? ii : -1;      // diag: require jj > ii

    float a0 = 0.f, a1 = 0.f, a2 = 0.f, a3 = 0.f;
    int w = tid >> 7;   // 0: even j, 1: odd j (other thread of the i covers the rest)

#define PAIR(J, RBASE, ACC) do {                                              \
    float4 cj4 = jtile[(J)];                                                  \
    int  wj   = __builtin_amdgcn_readfirstlane(__float_as_int(cj4.w));        \
    int  jres = wj & 1023;                                                    \
    int  jcb  = CBASE(wj);                                                    \
    float dx = ci.x - cj4.x, dy = ci.y - cj4.y, dz = ci.z - cj4.z;            \
    float d2 = fmaf(dx, dx, fmaf(dy, dy, dz * dz));                           \
    int sep = ires - jres; sep = sep < 0 ? -sep : sep;                        \
    bool v = (sep > 2) & (d2 < CUT2) & ((J) > ii_eff);                        \
    float dist  = __builtin_amdgcn_sqrtf(d2);                                 \
    float ds    = dist * (1.0f / 0.7f);                                       \
    float dsc   = fminf(ds, 27.0f);                                           \
    int   d0    = (int)dsc;                                                   \
    float alpha = ds - (float)d0;                                             \
    unsigned u  = SRC[(RBASE) + jcb + d0];                                    \
    float e0 = __uint_as_float(u << 16);                                      \
    float e1 = __uint_as_float(u & 0xFFFF0000u);                              \
    float en = fmaf(alpha, e1 - e0, e0);                                      \
    ACC += v ? en : 0.0f;                                                     \
} while (0)

    if (useLds) {
#define SRC lrow
#define CBASE(WJ) ((((WJ) >> 10) - tC) * BINS)
        #pragma unroll
        for (int s = 0; s < 16; ++s) {
            int j = 8 * s + w;
            PAIR(j,     rbL, a0);
            PAIR(j + 2, rbL, a1);
            PAIR(j + 4, rbL, a2);
            PAIR(j + 6, rbL, a3);
        }
#undef CBASE
#undef SRC
    } else {
#define SRC pk
#define CBASE(WJ) (((WJ) >> 10) * BINS)
        #pragma unroll
        for (int s = 0; s < 16; ++s) {
            int j = 8 * s + w;
            PAIR(j,     rbG, a0);
            PAIR(j + 2, rbG, a1);
            PAIR(j + 4, rbG, a2);
            PAIR(j + 6, rbG, a3);
        }
#undef CBASE
#undef SRC
    }
#undef PAIR

    float acc = (a0 + a1) + (a2 + a3);
    for (int off = 32; off > 0; off >>= 1)
        acc += __shfl_down(acc, off, 64);
    if ((tid & 63) == 0) wsum[tid >> 6] = acc;
    __syncthreads();
    if (tid == 0) partial[blockIdx.x] = (wsum[0] + wsum[1]) + (wsum[2] + wsum[3]);
}

// ---- K4: final reduction of per-block partials -> out[0]
__global__ __launch_bounds__(256) void reduce_k(const float* __restrict__ p, int n,
                                                float* __restrict__ out) {
    __shared__ float ws[4];
    float a = 0.f;
    for (int i = threadIdx.x; i < n; i += 256) a += p[i];
    for (int off = 32; off > 0; off >>= 1)
        a += __shfl_down(a, off, 64);
    if ((threadIdx.x & 63) == 0) ws[threadIdx.x >> 6] = a;
    __syncthreads();
    if (threadIdx.x == 0) out[0] = (ws[0] + ws[1]) + (ws[2] + ws[3]);
}

// ---- fallback (ws too small / odd N): unsorted, direct pot reads, atomics
__global__ __launch_bounds__(256) void dfire_pairs_fb(
    const float* __restrict__ coords, const int* __restrict__ res,
    const int* __restrict__ type, const float* __restrict__ pot,
    float* __restrict__ out, int T) {

    __shared__ float jx[128], jy[128], jz[128];
    __shared__ int   jres[128], jtype[128];

    int k = blockIdx.x;
    int r = (int)((2.0 * T + 1.0 - sqrt((2.0 * T + 1.0) * (2.0 * T + 1.0) - 8.0 * (double)k)) * 0.5);
    if (r < 0) r = 0;
    if (r > T - 1) r = T - 1;
    while (r > 0 && (r * T - r * (r - 1) / 2) > k) --r;
    while (((r + 1) * T - (r + 1) * r / 2) <= k) ++r;
    int c = r + (k - (r * T - r * (r - 1) / 2));

    int bi = r * 128, bj = c * 128;
    int tid = threadIdx.x;
    if (tid < 128) {
        int gj = bj + tid;
        jx[tid] = coords[3 * gj]; jy[tid] = coords[3 * gj + 1]; jz[tid] = coords[3 * gj + 2];
        jres[tid] = res[gj]; jtype[tid] = type[gj];
    }
    int ii = tid & 127;
    int gi = bi + ii;
    float ix = coords[3 * gi], iy = coords[3 * gi + 1], iz = coords[3 * gi + 2];
    int iresv = res[gi], it = type[gi];
    int ii_eff = (bi == bj) ? ii : -1;
    __syncthreads();

    float acc = 0.f;
    int jj = tid >> 7;
    for (int s = 0; s < 64; ++s, jj += 2) {
        float dx = ix - jx[jj], dy = iy - jy[jj], dz = iz - jz[jj];
        float d2 = dx * dx + dy * dy + dz * dz;
        float dist = sqrtf(d2) + 1e-8f;
        int sep = abs(iresv - jres[jj]);
        bool v = (sep > 2) & (dist < 19.6f) & (jj > ii_eff);
        if (v) {
            float ds = dist * (1.0f / 0.7f);
            int d0 = (int)fminf(ds, 27.0f);
            int d1 = (d0 + 1 < BINS) ? d0 + 1 : BINS - 1;
            float alpha = ds - (float)d0;
            int row = (jtype[jj] * NT + it) * BINS;
            float e0 = pot[row + d0], e1 = pot[row + d1];
            acc += e0 + alpha * (e1 - e0);
        }
    }
    for (int off = 32; off > 0; off >>= 1)
        acc += __shfl_down(acc, off, 64);
    if ((tid & 63) == 0) atomicAdd(out, acc);
}

extern "C" void kernel_launch(void* const* d_in, const int* in_sizes, int n_in,
                              void* d_out, int out_size, void* d_ws, size_t ws_size,
                              hipStream_t stream) {
    const float* coords = (const float*)d_in[0];
    const float* pot    = (const float*)d_in[1];
    const int*   res    = (const int*)d_in[2];
    const int*   type   = (const int*)d_in[3];
    // d_in[4], d_in[5] (i_idx/j_idx) unused: pairs generated from triu structure.

    const int N = in_sizes[2];
    float* out = (float*)d_out;

    const int T = N / 128;
    const int nblk = T * (T + 1) / 2;   // 2080 @ N=8192

    const size_t pkBytes   = (((size_t)LUT_ELEMS * 4) + 15) & ~(size_t)15;
    const size_t pcBytes   = (size_t)N * sizeof(float4);
    const size_t offsBytes = 128 * sizeof(int);
    const size_t partBytes = (size_t)nblk * sizeof(float);
    const size_t need = pkBytes + pcBytes + offsBytes + partBytes;

    if (ws_size >= need && (N % 128) == 0) {
        char* w = (char*)d_ws;
        unsigned* pk      = (unsigned*)w;   w += pkBytes;
        float4*   pc      = (float4*)w;     w += pcBytes;
        int*      offs    = (int*)w;        w += offsBytes;
        float*    partial = (float*)w;

        const int prepBlocks = (LUT_ELEMS + 255) / 256;   // 791
        prep_k<<<prepBlocks + 1, 256, 0, stream>>>(pot, type, N, pk, offs);
        scatter_k<<<(N + 255) / 256, 256, 0, stream>>>(coords, res, type, offs, pc, N);
        dfire_pairs8<<<nblk, 256, 0, stream>>>(pc, pk, partial, T);
        reduce_k<<<1, 256, 0, stream>>>(partial, nblk, out);
    } else {
        hipMemsetAsync(out, 0, sizeof(float), stream);
        dfire_pairs_fb<<<T * (T + 1) / 2, 256, 0, stream>>>(coords, res, type, pot, out, T);
    }
}